// Round 18
// baseline (195.840 us; speedup 1.0000x reference)
//
#include <hip/hip_runtime.h>
#include <stdint.h>

#define B_ 8
#define N_ 2048
#define D_ 768

typedef unsigned short u16;
typedef unsigned int u32;
typedef __attribute__((ext_vector_type(8))) short bf16x8;
typedef __attribute__((ext_vector_type(8))) unsigned short u16x8;
typedef __attribute__((ext_vector_type(4))) float f32x4;

static constexpr float INV_SCALE = 0.10825317547305482f; // 3/sqrt(768)

__device__ __forceinline__ u16 f2bf(float f) {
  union { float f; unsigned u; } v; v.f = f;
  return (u16)((v.u + 0x7FFFu + ((v.u >> 16) & 1u)) >> 16);
}
__device__ __forceinline__ float bf2f(u16 h) {
  union { unsigned u; float f; } v; v.u = ((unsigned)h) << 16;
  return v.f;
}
__device__ __forceinline__ f32x4 mfma16(bf16x8 a, bf16x8 b, f32x4 c) {
  return __builtin_amdgcn_mfma_f32_16x16x32_bf16(a, b, c, 0, 0, 0);
}
__device__ __forceinline__ void gl_lds16(const void* g, void* l) {
  __builtin_amdgcn_global_load_lds(
      (const __attribute__((address_space(1))) u32*)g,
      (__attribute__((address_space(3))) u32*)l, 16, 0, 0);
}

// ---------------- K0: cast x, Wq, Wk, Wv to bf16 ----------------
__global__ __launch_bounds__(256) void cast_kernel(
    const float* __restrict__ x, const float* __restrict__ wq,
    const float* __restrict__ wk, const float* __restrict__ wv,
    u16* __restrict__ xb, u16* __restrict__ wqb,
    u16* __restrict__ wkb, u16* __restrict__ wvb) {
  const long NX = (long)B_ * N_ * D_;
  const long NW = (long)D_ * D_;
  long i = ((long)blockIdx.x * 256 + threadIdx.x) * 8;
  const float* src; u16* dst; long off;
  if (i < NX) { src = x; dst = xb; off = i; }
  else {
    long j = i - NX;
    int seg = (int)(j / NW);
    off = j - (long)seg * NW;
    src = seg == 0 ? wq : (seg == 1 ? wk : wv);
    dst = seg == 0 ? wqb : (seg == 1 ? wkb : wvb);
  }
  float4 a = *(const float4*)(src + off);
  float4 b = *(const float4*)(src + off + 4);
  u16x8 o;
  o[0]=f2bf(a.x); o[1]=f2bf(a.y); o[2]=f2bf(a.z); o[3]=f2bf(a.w);
  o[4]=f2bf(b.x); o[5]=f2bf(b.y); o[6]=f2bf(b.z); o[7]=f2bf(b.w);
  *(u16x8*)(dst + off) = o;
}

// ==== bf16 256x256 BK=64 core, 2M x 4N waves (qk_exp) ====
// R18 delta: STAGE_B moved to tile start (full-tile prefetch distance for
// B, was half-tile); counted wait vmcnt(8) = A(t+1)4 + B(t+1)4 in flight,
// drains A(t),B(t). WAR-safe: buffer Y last read in tile t-1, retired
// before its closing barrier.
template<int NT, int NF>
__device__ __forceinline__ void gemm256(
    const u16* __restrict__ Ag, long lda,
    const u16* __restrict__ Bg, long ldb,
    f32x4 (&acc)[8][NF]) {
  __shared__ u16 Ab[2][16384];
  __shared__ u16 Bb[2][NF * 4096];
  const int t_ = threadIdx.x, l = t_ & 63, w = t_ >> 6;
  const int lr = l & 15, kq = l >> 4;
  const int wm = w >> 2, wn = w & 3;
  const int arow = wm * 128, brow = wn * (NF * 16);
  const int s_rowl = l >> 3;
  const int s_sl = (l & 7) ^ (l >> 3);
  auto STAGE_A = [&](u16* As, int kt) {
    #pragma unroll
    for (int j = 0; j < 4; ++j) {
      const int row = j * 64 + w * 8 + s_rowl;
      gl_lds16(Ag + (long)row * lda + kt * 64 + s_sl * 8,
               As + ((j * 8192 + w * 1024) >> 1));
    }
  };
  auto STAGE_B = [&](u16* Bs, int kt) {
    #pragma unroll
    for (int j = 0; j < NF; ++j) {
      const int row = j * 64 + w * 8 + s_rowl;
      gl_lds16(Bg + (long)row * ldb + kt * 64 + s_sl * 8,
               Bs + ((j * 8192 + w * 1024) >> 1));
    }
  };

#define TILE(XA, XB, YA, YB, kt, DOST)                                       \
  {                                                                          \
    if (DOST) {                                                              \
      STAGE_A(YA, (kt) + 1);                                                 \
      STAGE_B(YB, (kt) + 1);                                                 \
      asm volatile("s_waitcnt vmcnt(8)" ::: "memory");                       \
    } else {                                                                 \
      asm volatile("s_waitcnt vmcnt(0)" ::: "memory");                       \
    }                                                                        \
    __builtin_amdgcn_s_barrier();                                            \
    asm volatile("" ::: "memory");                                           \
    bf16x8 bf[NF][2];                                                        \
    _Pragma("unroll")                                                        \
    for (int nf = 0; nf < NF; ++nf) {                                        \
      const int row = brow + nf * 16 + lr;                                   \
      _Pragma("unroll")                                                      \
      for (int ks = 0; ks < 2; ++ks)                                         \
        bf[nf][ks] = *(const bf16x8*)(XB + row * 64 +                        \
                        (((4 * ks + kq) ^ (lr & 7)) * 8));                   \
    }                                                                        \
    {                                                                        \
      bf16x8 af[4][2];                                                       \
      _Pragma("unroll")                                                      \
      for (int mf = 0; mf < 4; ++mf) {                                       \
        const int row = arow + mf * 16 + lr;                                 \
        _Pragma("unroll")                                                    \
        for (int ks = 0; ks < 2; ++ks)                                       \
          af[mf][ks] = *(const bf16x8*)(XA + row * 64 +                      \
                          (((4 * ks + kq) ^ (lr & 7)) * 8));                 \
      }                                                                      \
      __builtin_amdgcn_s_setprio(1);                                         \
      _Pragma("unroll")                                                      \
      for (int ks = 0; ks < 2; ++ks)                                         \
        _Pragma("unroll")                                                    \
        for (int mf = 0; mf < 4; ++mf)                                       \
          _Pragma("unroll")                                                  \
          for (int nf = 0; nf < NF; ++nf)                                    \
            acc[mf][nf] = mfma16(af[mf][ks], bf[nf][ks], acc[mf][nf]);       \
      __builtin_amdgcn_s_setprio(0);                                         \
    }                                                                        \
    {                                                                        \
      bf16x8 af[4][2];                                                       \
      _Pragma("unroll")                                                      \
      for (int mf = 0; mf < 4; ++mf) {                                       \
        const int row = arow + 64 + mf * 16 + lr;                            \
        _Pragma("unroll")                                                    \
        for (int ks = 0; ks < 2; ++ks)                                       \
          af[mf][ks] = *(const bf16x8*)(XA + row * 64 +                      \
                          (((4 * ks + kq) ^ (lr & 7)) * 8));                 \
      }                                                                      \
      __builtin_amdgcn_s_setprio(1);                                         \
      _Pragma("unroll")                                                      \
      for (int ks = 0; ks < 2; ++ks)                                         \
        _Pragma("unroll")                                                    \
        for (int mf = 0; mf < 4; ++mf)                                       \
          _Pragma("unroll")                                                  \
          for (int nf = 0; nf < NF; ++nf)                                    \
            acc[4 + mf][nf] = mfma16(af[mf][ks], bf[nf][ks], acc[4 + mf][nf]); \
      __builtin_amdgcn_s_setprio(0);                                         \
    }                                                                        \
    asm volatile("" ::: "memory");                                           \
    __builtin_amdgcn_s_barrier();                                            \
  }

  STAGE_A(Ab[0], 0);
  STAGE_B(Bb[0], 0);
  for (int t2 = 0; t2 < NT; t2 += 2) {
    TILE(Ab[0], Bb[0], Ab[1], Bb[1], t2, true)
    TILE(Ab[1], Bb[1], Ab[0], Bb[0], t2 + 1, (t2 + 2 < NT))
  }
#undef TILE
}

// ==== bf16 128x192 BK=64 core, 2M x 4N waves, 80 KB LDS -> 2 blocks/CU ====
// R18 delta: STAGE_B at tile start; vmcnt(5) = A(t+1)2 + B(t+1)3 in flight.
template<int NT>
__device__ __forceinline__ void gemm128(
    const u16* __restrict__ Ag, long lda,
    const u16* __restrict__ Bg, long ldb,
    f32x4 (&acc)[4][3]) {
  __shared__ u16 Ab[2][8192];
  __shared__ u16 Bb[2][12288];
  const int t_ = threadIdx.x, l = t_ & 63, w = t_ >> 6;
  const int lr = l & 15, kq = l >> 4;
  const int wm = w >> 2, wn = w & 3;
  const int arow = wm * 64, brow = wn * 48;
  const int s_rowl = l >> 3;
  const int s_sl = (l & 7) ^ (l >> 3);
  auto STAGE_A = [&](u16* As, int kt) {
    #pragma unroll
    for (int j = 0; j < 2; ++j) {
      const int row = j * 64 + w * 8 + s_rowl;
      gl_lds16(Ag + (long)row * lda + kt * 64 + s_sl * 8,
               As + ((j * 8192 + w * 1024) >> 1));
    }
  };
  auto STAGE_B = [&](u16* Bs, int kt) {
    #pragma unroll
    for (int j = 0; j < 3; ++j) {
      const int row = j * 64 + w * 8 + s_rowl;
      gl_lds16(Bg + (long)row * ldb + kt * 64 + s_sl * 8,
               Bs + ((j * 8192 + w * 1024) >> 1));
    }
  };

#define TILE(XA, XB, YA, YB, kt, DOST)                                       \
  {                                                                          \
    if (DOST) {                                                              \
      STAGE_A(YA, (kt) + 1);                                                 \
      STAGE_B(YB, (kt) + 1);                                                 \
      asm volatile("s_waitcnt vmcnt(5)" ::: "memory");                       \
    } else {                                                                 \
      asm volatile("s_waitcnt vmcnt(0)" ::: "memory");                       \
    }                                                                        \
    __builtin_amdgcn_s_barrier();                                            \
    asm volatile("" ::: "memory");                                           \
    bf16x8 bf[3][2];                                                         \
    _Pragma("unroll")                                                        \
    for (int nf = 0; nf < 3; ++nf) {                                         \
      const int row = brow + nf * 16 + lr;                                   \
      _Pragma("unroll")                                                      \
      for (int ks = 0; ks < 2; ++ks)                                         \
        bf[nf][ks] = *(const bf16x8*)(XB + row * 64 +                        \
                        (((4 * ks + kq) ^ (lr & 7)) * 8));                   \
    }                                                                        \
    {                                                                        \
      bf16x8 af[2][2];                                                       \
      _Pragma("unroll")                                                      \
      for (int mf = 0; mf < 2; ++mf) {                                       \
        const int row = arow + mf * 16 + lr;                                 \
        _Pragma("unroll")                                                    \
        for (int ks = 0; ks < 2; ++ks)                                       \
          af[mf][ks] = *(const bf16x8*)(XA + row * 64 +                      \
                          (((4 * ks + kq) ^ (lr & 7)) * 8));                 \
      }                                                                      \
      __builtin_amdgcn_s_setprio(1);                                         \
      _Pragma("unroll")                                                      \
      for (int ks = 0; ks < 2; ++ks)                                         \
        _Pragma("unroll")                                                    \
        for (int mf = 0; mf < 2; ++mf)                                       \
          _Pragma("unroll")                                                  \
          for (int nf = 0; nf < 3; ++nf)                                     \
            acc[mf][nf] = mfma16(af[mf][ks], bf[nf][ks], acc[mf][nf]);       \
      __builtin_amdgcn_s_setprio(0);                                         \
    }                                                                        \
    {                                                                        \
      bf16x8 af[2][2];                                                       \
      _Pragma("unroll")                                                      \
      for (int mf = 0; mf < 2; ++mf) {                                       \
        const int row = arow + 32 + mf * 16 + lr;                            \
        _Pragma("unroll")                                                    \
        for (int ks = 0; ks < 2; ++ks)                                       \
          af[mf][ks] = *(const bf16x8*)(XA + row * 64 +                      \
                          (((4 * ks + kq) ^ (lr & 7)) * 8));                 \
      }                                                                      \
      __builtin_amdgcn_s_setprio(1);                                         \
      _Pragma("unroll")                                                      \
      for (int ks = 0; ks < 2; ++ks)                                         \
        _Pragma("unroll")                                                    \
        for (int mf = 0; mf < 2; ++mf)                                       \
          _Pragma("unroll")                                                  \
          for (int nf = 0; nf < 3; ++nf)                                     \
            acc[2 + mf][nf] = mfma16(af[mf][ks], bf[nf][ks], acc[2 + mf][nf]); \
      __builtin_amdgcn_s_setprio(0);                                         \
    }                                                                        \
    asm volatile("" ::: "memory");                                           \
    __builtin_amdgcn_s_barrier();                                            \
  }

  STAGE_A(Ab[0], 0);
  STAGE_B(Bb[0], 0);
  for (int t2 = 0; t2 < NT; t2 += 2) {
    TILE(Ab[0], Bb[0], Ab[1], Bb[1], t2, true)
    TILE(Ab[1], Bb[1], Ab[0], Bb[0], t2 + 1, (t2 + 2 < NT))
  }
#undef TILE
}

// ---------------- K1: Q/K/V = x @ W^T + b (Q scaled) ----------------
// tile 128x192 -> grid 1536 = 6.0 EXACT rounds at 2 blk/CU; XCD = rt-band.
__global__ __launch_bounds__(512, 4) void qkv_gemm(
    const u16* __restrict__ xb,
    const u16* __restrict__ wq, const u16* __restrict__ wk, const u16* __restrict__ wv,
    const float* __restrict__ bq, const float* __restrict__ bk, const float* __restrict__ bv,
    u16* __restrict__ Qs, u16* __restrict__ Kb, u16* __restrict__ Vb) {
  const int lin = blockIdx.x;
  const int xcd = lin & 7, inner = lin >> 3;          // inner: 0..191
  const int rt = xcd * 16 + (inner & 15);
  const int ct = inner >> 4;                          // 0..11 over 3 mats
  const int mat = ct >> 2;
  const u16* W = mat == 0 ? wq : (mat == 1 ? wk : wv);
  const float* bias = mat == 0 ? bq : (mat == 1 ? bk : bv);
  u16* out = mat == 0 ? Qs : (mat == 1 ? Kb : Vb);
  const float scl = mat == 0 ? INV_SCALE : 1.0f;
  const int rbase = rt * 128, cbase = (ct & 3) * 192;

  f32x4 acc[4][3] = {};
  gemm128<D_ / 64>(xb + (long)rbase * D_, D_, W + (long)cbase * D_, D_, acc);

  const int l = threadIdx.x & 63, w = threadIdx.x >> 6;
  const int lr = l & 15, orow = (l >> 4) * 4;
  const int wm = w >> 2, wn = w & 3;
  #pragma unroll
  for (int mf = 0; mf < 4; ++mf)
    #pragma unroll
    for (int nf = 0; nf < 3; ++nf) {
      int col = cbase + wn * 48 + nf * 16 + lr;
      float bc = bias[col];
      #pragma unroll
      for (int r = 0; r < 4; ++r) {
        int row = rbase + wm * 64 + mf * 16 + orow + r;
        out[(long)row * D_ + col] = f2bf((acc[mf][nf][r] + bc) * scl);
      }
    }
}

// ---------------- K2: P = exp(Q.K^T) bf16, den partials ----------------
// grid 512 = 2.0 exact rounds; XCD = one b.
__global__ __launch_bounds__(512, 1) void qk_exp(
    const u16* __restrict__ Qs, const u16* __restrict__ Kb,
    u16* __restrict__ P, float* __restrict__ denpart) {
  const int lin = blockIdx.x;
  const int b = lin & 7, inner = lin >> 3;
  const int kblk = inner & 7, qblk = inner >> 3;

  f32x4 acc[8][4] = {};
  gemm256<D_ / 64, 4>(Qs + ((long)b * N_ + qblk * 256) * D_, D_,
                      Kb + ((long)b * N_ + kblk * 256) * D_, D_, acc);

  const int tt = threadIdx.x, l = tt & 63, w = tt >> 6;
  const int lr = l & 15, orow = (l >> 4) * 4;
  const int wm = w >> 2, wn = w & 3;
  float csum[4] = {0.f, 0.f, 0.f, 0.f};
  #pragma unroll
  for (int mf = 0; mf < 8; ++mf)
    #pragma unroll
    for (int nf = 0; nf < 4; ++nf) {
      long kk = kblk * 256 + wn * 64 + nf * 16 + lr;
      #pragma unroll
      for (int r = 0; r < 4; ++r) {
        long q = qblk * 256 + wm * 128 + mf * 16 + orow + r;
        float e = __expf(acc[mf][nf][r]);
        u16 pe = f2bf(e);
        P[((long)b * N_ + q) * N_ + kk] = pe;
        csum[nf] += bf2f(pe);
      }
    }
  #pragma unroll
  for (int nf = 0; nf < 4; ++nf) {
    csum[nf] += __shfl_xor(csum[nf], 16);
    csum[nf] += __shfl_xor(csum[nf], 32);
  }
  if (l < 16) {
    #pragma unroll
    for (int nf = 0; nf < 4; ++nf)
      denpart[((long)(qblk * 2 + wm) * B_ + b) * N_ +
              kblk * 256 + wn * 64 + nf * 16 + l] = csum[nf];
  }
}

// ---------------- K3: VsT[b][d][k] = V[b][k][d] / den[b][k] ----------------
__global__ __launch_bounds__(256) void scale_transpose(
    const u16* __restrict__ Vb, const float* __restrict__ denpart,
    u16* __restrict__ VsT) {
  const int b = blockIdx.z, k0 = blockIdx.y * 64, d0 = blockIdx.x * 64;
  __shared__ float tile[64][65];
  __shared__ float invden[64];
  const int t = threadIdx.x;
  if (t < 64) {
    float s = 0.f;
    for (int qs = 0; qs < 16; ++qs)
      s += denpart[((long)qs * B_ + b) * N_ + k0 + t];
    invden[t] = 1.0f / s;
  }
  __syncthreads();
  #pragma unroll
  for (int h = 0; h < 2; ++h) {
    const int kl = (t >> 3) + h * 32;
    const int d8 = (t & 7) * 8;
    bf16x8 v = *(const bf16x8*)(Vb + ((long)b * N_ + k0 + kl) * D_ + d0 + d8);
    const float s = invden[kl];
    #pragma unroll
    for (int j = 0; j < 8; ++j)
      tile[d8 + j][kl] = bf2f((u16)v[j]) * s;
  }
  __syncthreads();
  #pragma unroll
  for (int h = 0; h < 2; ++h) {
    const int dl = (t >> 3) + h * 32;
    const int k8 = (t & 7) * 8;
    u16x8 o;
    #pragma unroll
    for (int j = 0; j < 8; ++j)
      o[j] = f2bf(tile[dl][k8 + j]);
    *(u16x8*)(VsT + ((long)b * D_ + d0 + dl) * N_ + k0 + k8) = o;
  }
}

// ---------------- K4: out = P @ Vs + xb (bf16 residual) ----------------
// tile 128x192 -> grid 512 = 2.0 EXACT rounds, 2 blk/CU; XCD = one b.
__global__ __launch_bounds__(512, 4) void pv_gemm(
    const u16* __restrict__ P, const u16* __restrict__ VsT,
    const u16* __restrict__ xb, float* __restrict__ out) {
  const int lin = blockIdx.x;
  const int b = lin & 7, inner = lin >> 3;            // inner: 0..63
  const int qt = inner & 15, dt = inner >> 4;         // 16 qt x 4 dt
  const int q0 = qt * 128, d0 = dt * 192;

  f32x4 acc[4][3] = {};
  gemm128<N_ / 64>(P + ((long)b * N_ + q0) * N_, N_,
                   VsT + ((long)b * D_ + d0) * N_, N_, acc);

  const int l = threadIdx.x & 63, w = threadIdx.x >> 6;
  const int lr = l & 15, orow = (l >> 4) * 4;
  const int wm = w >> 2, wn = w & 3;
  #pragma unroll
  for (int mf = 0; mf < 4; ++mf)
    #pragma unroll
    for (int nf = 0; nf < 3; ++nf) {
      int dd = d0 + wn * 48 + nf * 16 + lr;
      #pragma unroll
      for (int r = 0; r < 4; ++r) {
        int q = q0 + wm * 64 + mf * 16 + orow + r;
        long idx = ((long)b * N_ + q) * D_ + dd;
        out[idx] = acc[mf][nf][r] + bf2f(xb[idx]);
      }
    }
}

extern "C" void kernel_launch(void* const* d_in, const int* in_sizes, int n_in,
                              void* d_out, int out_size, void* d_ws, size_t ws_size,
                              hipStream_t stream) {
  const float* x  = (const float*)d_in[0];
  const float* Wq = (const float*)d_in[1];
  const float* bq = (const float*)d_in[2];
  const float* Wk = (const float*)d_in[3];
  const float* bk = (const float*)d_in[4];
  const float* Wv = (const float*)d_in[5];
  const float* bv = (const float*)d_in[6];

  char* ws = (char*)d_ws;
  u16* xb  = (u16*)(ws + 0);                          // 25165824 B (live to pv)
  u16* wqb = (u16*)(ws + 25165824);
  u16* wkb = (u16*)(ws + 26345472);
  u16* wvb = (u16*)(ws + 27525120);
  u16* Qs  = (u16*)(ws + 28704768);
  u16* Kb  = (u16*)(ws + 53870592);
  u16* Vb  = (u16*)(ws + 79036416);
  u16* VsT = (u16*)(ws + 104202240);                  // 25165824 B
  u16* P   = (u16*)(ws + 129368064);                  // 67108864 B
  float* denpart = (float*)(ws + 196476928);          // 1048576 B
  (void)in_sizes; (void)n_in; (void)out_size; (void)ws_size;

  cast_kernel<<<7008, 256, 0, stream>>>(x, Wq, Wk, Wv, xb, wqb, wkb, wvb);
  qkv_gemm<<<1536, 512, 0, stream>>>(xb, wqb, wkb, wvb, bq, bk, bv, Qs, Kb, Vb);
  qk_exp<<<512, 512, 0, stream>>>(Qs, Kb, P, denpart);
  scale_transpose<<<dim3(12, 32, 8), 256, 0, stream>>>(Vb, denpart, VsT);
  pv_gemm<<<512, 512, 0, stream>>>(P, VsT, xb, (float*)d_out);
}

// Round 19
// 191.390 us; speedup vs baseline: 1.0233x; 1.0233x over previous
//
#include <hip/hip_runtime.h>
#include <stdint.h>

#define B_ 8
#define N_ 2048
#define D_ 768

typedef unsigned short u16;
typedef unsigned int u32;
typedef __attribute__((ext_vector_type(8))) short bf16x8;
typedef __attribute__((ext_vector_type(8))) unsigned short u16x8;
typedef __attribute__((ext_vector_type(4))) float f32x4;

static constexpr float INV_SCALE = 0.10825317547305482f; // 3/sqrt(768)

__device__ __forceinline__ u16 f2bf(float f) {
  union { float f; unsigned u; } v; v.f = f;
  return (u16)((v.u + 0x7FFFu + ((v.u >> 16) & 1u)) >> 16);
}
__device__ __forceinline__ float bf2f(u16 h) {
  union { unsigned u; float f; } v; v.u = ((unsigned)h) << 16;
  return v.f;
}
__device__ __forceinline__ f32x4 mfma16(bf16x8 a, bf16x8 b, f32x4 c) {
  return __builtin_amdgcn_mfma_f32_16x16x32_bf16(a, b, c, 0, 0, 0);
}
__device__ __forceinline__ void gl_lds16(const void* g, void* l) {
  __builtin_amdgcn_global_load_lds(
      (const __attribute__((address_space(1))) u32*)g,
      (__attribute__((address_space(3))) u32*)l, 16, 0, 0);
}

// ---------------- K0: cast x, Wq, Wk, Wv to bf16 ----------------
__global__ __launch_bounds__(256) void cast_kernel(
    const float* __restrict__ x, const float* __restrict__ wq,
    const float* __restrict__ wk, const float* __restrict__ wv,
    u16* __restrict__ xb, u16* __restrict__ wqb,
    u16* __restrict__ wkb, u16* __restrict__ wvb) {
  const long NX = (long)B_ * N_ * D_;
  const long NW = (long)D_ * D_;
  long i = ((long)blockIdx.x * 256 + threadIdx.x) * 8;
  const float* src; u16* dst; long off;
  if (i < NX) { src = x; dst = xb; off = i; }
  else {
    long j = i - NX;
    int seg = (int)(j / NW);
    off = j - (long)seg * NW;
    src = seg == 0 ? wq : (seg == 1 ? wk : wv);
    dst = seg == 0 ? wqb : (seg == 1 ? wkb : wvb);
  }
  float4 a = *(const float4*)(src + off);
  float4 b = *(const float4*)(src + off + 4);
  u16x8 o;
  o[0]=f2bf(a.x); o[1]=f2bf(a.y); o[2]=f2bf(a.z); o[3]=f2bf(a.w);
  o[4]=f2bf(b.x); o[5]=f2bf(b.y); o[6]=f2bf(b.z); o[7]=f2bf(b.w);
  *(u16x8*)(dst + off) = o;
}

// ==== bf16 256x256 BK=64 core, 2M x 4N waves (R12/R17-verified; qk_exp) ====
// Mid-tile STAGE_B (issue-slot balanced); counted vmcnt(4) never 0 mid-loop;
// swizzle both sides: phys 16B-slot = logical ^ (row&7), conflicts = 0.
template<int NT, int NF>
__device__ __forceinline__ void gemm256(
    const u16* __restrict__ Ag, long lda,
    const u16* __restrict__ Bg, long ldb,
    f32x4 (&acc)[8][NF]) {
  __shared__ u16 Ab[2][16384];
  __shared__ u16 Bb[2][NF * 4096];
  const int t_ = threadIdx.x, l = t_ & 63, w = t_ >> 6;
  const int lr = l & 15, kq = l >> 4;
  const int wm = w >> 2, wn = w & 3;
  const int arow = wm * 128, brow = wn * (NF * 16);
  const int s_rowl = l >> 3;
  const int s_sl = (l & 7) ^ (l >> 3);
  auto STAGE_A = [&](u16* As, int kt) {
    #pragma unroll
    for (int j = 0; j < 4; ++j) {
      const int row = j * 64 + w * 8 + s_rowl;
      gl_lds16(Ag + (long)row * lda + kt * 64 + s_sl * 8,
               As + ((j * 8192 + w * 1024) >> 1));
    }
  };
  auto STAGE_B = [&](u16* Bs, int kt) {
    #pragma unroll
    for (int j = 0; j < NF; ++j) {
      const int row = j * 64 + w * 8 + s_rowl;
      gl_lds16(Bg + (long)row * ldb + kt * 64 + s_sl * 8,
               Bs + ((j * 8192 + w * 1024) >> 1));
    }
  };

#define TILE(XA, XB, YA, YB, kt, DOST)                                       \
  {                                                                          \
    if (DOST) {                                                              \
      STAGE_A(YA, (kt) + 1);                                                 \
      asm volatile("s_waitcnt vmcnt(4)" ::: "memory");                       \
    } else {                                                                 \
      asm volatile("s_waitcnt vmcnt(0)" ::: "memory");                       \
    }                                                                        \
    __builtin_amdgcn_s_barrier();                                            \
    asm volatile("" ::: "memory");                                           \
    bf16x8 bf[NF][2];                                                        \
    _Pragma("unroll")                                                        \
    for (int nf = 0; nf < NF; ++nf) {                                        \
      const int row = brow + nf * 16 + lr;                                   \
      _Pragma("unroll")                                                      \
      for (int ks = 0; ks < 2; ++ks)                                         \
        bf[nf][ks] = *(const bf16x8*)(XB + row * 64 +                        \
                        (((4 * ks + kq) ^ (lr & 7)) * 8));                   \
    }                                                                        \
    {                                                                        \
      bf16x8 af[4][2];                                                       \
      _Pragma("unroll")                                                      \
      for (int mf = 0; mf < 4; ++mf) {                                       \
        const int row = arow + mf * 16 + lr;                                 \
        _Pragma("unroll")                                                    \
        for (int ks = 0; ks < 2; ++ks)                                       \
          af[mf][ks] = *(const bf16x8*)(XA + row * 64 +                      \
                          (((4 * ks + kq) ^ (lr & 7)) * 8));                 \
      }                                                                      \
      __builtin_amdgcn_s_setprio(1);                                         \
      _Pragma("unroll")                                                      \
      for (int ks = 0; ks < 2; ++ks)                                         \
        _Pragma("unroll")                                                    \
        for (int mf = 0; mf < 4; ++mf)                                       \
          _Pragma("unroll")                                                  \
          for (int nf = 0; nf < NF; ++nf)                                    \
            acc[mf][nf] = mfma16(af[mf][ks], bf[nf][ks], acc[mf][nf]);       \
      __builtin_amdgcn_s_setprio(0);                                         \
    }                                                                        \
    if (DOST) STAGE_B(YB, (kt) + 1);                                         \
    {                                                                        \
      bf16x8 af[4][2];                                                       \
      _Pragma("unroll")                                                      \
      for (int mf = 0; mf < 4; ++mf) {                                       \
        const int row = arow + 64 + mf * 16 + lr;                            \
        _Pragma("unroll")                                                    \
        for (int ks = 0; ks < 2; ++ks)                                       \
          af[mf][ks] = *(const bf16x8*)(XA + row * 64 +                      \
                          (((4 * ks + kq) ^ (lr & 7)) * 8));                 \
      }                                                                      \
      __builtin_amdgcn_s_setprio(1);                                         \
      _Pragma("unroll")                                                      \
      for (int ks = 0; ks < 2; ++ks)                                         \
        _Pragma("unroll")                                                    \
        for (int mf = 0; mf < 4; ++mf)                                       \
          _Pragma("unroll")                                                  \
          for (int nf = 0; nf < NF; ++nf)                                    \
            acc[4 + mf][nf] = mfma16(af[mf][ks], bf[nf][ks], acc[4 + mf][nf]); \
      __builtin_amdgcn_s_setprio(0);                                         \
    }                                                                        \
    asm volatile("" ::: "memory");                                           \
    __builtin_amdgcn_s_barrier();                                            \
  }

  STAGE_A(Ab[0], 0);
  STAGE_B(Bb[0], 0);
  for (int t2 = 0; t2 < NT; t2 += 2) {
    TILE(Ab[0], Bb[0], Ab[1], Bb[1], t2, true)
    TILE(Ab[1], Bb[1], Ab[0], Bb[0], t2 + 1, (t2 + 2 < NT))
  }
#undef TILE
}

// ==== bf16 128x192 BK=64 core, 2M x 4N waves, 80 KB LDS -> 2 blocks/CU ====
// R17-verified: wave tile 64x48, mid-tile STAGE_B, vmcnt(2); co-resident
// block fills barrier/vmcnt stalls (TLP) — qkv 62.3 us, MfmaUtil 35-38%.
template<int NT>
__device__ __forceinline__ void gemm128(
    const u16* __restrict__ Ag, long lda,
    const u16* __restrict__ Bg, long ldb,
    f32x4 (&acc)[4][3]) {
  __shared__ u16 Ab[2][8192];
  __shared__ u16 Bb[2][12288];
  const int t_ = threadIdx.x, l = t_ & 63, w = t_ >> 6;
  const int lr = l & 15, kq = l >> 4;
  const int wm = w >> 2, wn = w & 3;
  const int arow = wm * 64, brow = wn * 48;
  const int s_rowl = l >> 3;
  const int s_sl = (l & 7) ^ (l >> 3);
  auto STAGE_A = [&](u16* As, int kt) {
    #pragma unroll
    for (int j = 0; j < 2; ++j) {
      const int row = j * 64 + w * 8 + s_rowl;
      gl_lds16(Ag + (long)row * lda + kt * 64 + s_sl * 8,
               As + ((j * 8192 + w * 1024) >> 1));
    }
  };
  auto STAGE_B = [&](u16* Bs, int kt) {
    #pragma unroll
    for (int j = 0; j < 3; ++j) {
      const int row = j * 64 + w * 8 + s_rowl;
      gl_lds16(Bg + (long)row * ldb + kt * 64 + s_sl * 8,
               Bs + ((j * 8192 + w * 1024) >> 1));
    }
  };

#define TILE(XA, XB, YA, YB, kt, DOST)                                       \
  {                                                                          \
    if (DOST) {                                                              \
      STAGE_A(YA, (kt) + 1);                                                 \
      asm volatile("s_waitcnt vmcnt(2)" ::: "memory");                       \
    } else {                                                                 \
      asm volatile("s_waitcnt vmcnt(0)" ::: "memory");                       \
    }                                                                        \
    __builtin_amdgcn_s_barrier();                                            \
    asm volatile("" ::: "memory");                                           \
    bf16x8 bf[3][2];                                                         \
    _Pragma("unroll")                                                        \
    for (int nf = 0; nf < 3; ++nf) {                                         \
      const int row = brow + nf * 16 + lr;                                   \
      _Pragma("unroll")                                                      \
      for (int ks = 0; ks < 2; ++ks)                                         \
        bf[nf][ks] = *(const bf16x8*)(XB + row * 64 +                        \
                        (((4 * ks + kq) ^ (lr & 7)) * 8));                   \
    }                                                                        \
    {                                                                        \
      bf16x8 af[2][2];                                                       \
      _Pragma("unroll")                                                      \
      for (int mf = 0; mf < 2; ++mf) {                                       \
        const int row = arow + mf * 16 + lr;                                 \
        _Pragma("unroll")                                                    \
        for (int ks = 0; ks < 2; ++ks)                                       \
          af[mf][ks] = *(const bf16x8*)(XA + row * 64 +                      \
                          (((4 * ks + kq) ^ (lr & 7)) * 8));                 \
      }                                                                      \
      __builtin_amdgcn_s_setprio(1);                                         \
      _Pragma("unroll")                                                      \
      for (int ks = 0; ks < 2; ++ks)                                         \
        _Pragma("unroll")                                                    \
        for (int mf = 0; mf < 2; ++mf)                                       \
          _Pragma("unroll")                                                  \
          for (int nf = 0; nf < 3; ++nf)                                     \
            acc[mf][nf] = mfma16(af[mf][ks], bf[nf][ks], acc[mf][nf]);       \
      __builtin_amdgcn_s_setprio(0);                                         \
    }                                                                        \
    if (DOST) STAGE_B(YB, (kt) + 1);                                         \
    {                                                                        \
      bf16x8 af[2][2];                                                       \
      _Pragma("unroll")                                                      \
      for (int mf = 0; mf < 2; ++mf) {                                       \
        const int row = arow + 32 + mf * 16 + lr;                            \
        _Pragma("unroll")                                                    \
        for (int ks = 0; ks < 2; ++ks)                                       \
          af[mf][ks] = *(const bf16x8*)(XA + row * 64 +                      \
                          (((4 * ks + kq) ^ (lr & 7)) * 8));                 \
      }                                                                      \
      __builtin_amdgcn_s_setprio(1);                                         \
      _Pragma("unroll")                                                      \
      for (int ks = 0; ks < 2; ++ks)                                         \
        _Pragma("unroll")                                                    \
        for (int mf = 0; mf < 2; ++mf)                                       \
          _Pragma("unroll")                                                  \
          for (int nf = 0; nf < 3; ++nf)                                     \
            acc[2 + mf][nf] = mfma16(af[mf][ks], bf[nf][ks], acc[2 + mf][nf]); \
      __builtin_amdgcn_s_setprio(0);                                         \
    }                                                                        \
    asm volatile("" ::: "memory");                                           \
    __builtin_amdgcn_s_barrier();                                            \
  }

  STAGE_A(Ab[0], 0);
  STAGE_B(Bb[0], 0);
  for (int t2 = 0; t2 < NT; t2 += 2) {
    TILE(Ab[0], Bb[0], Ab[1], Bb[1], t2, true)
    TILE(Ab[1], Bb[1], Ab[0], Bb[0], t2 + 1, (t2 + 2 < NT))
  }
#undef TILE
}

// ---------------- K1: Q/K/V = x @ W^T + b (Q scaled) ----------------
// tile 128x192 -> grid 1536 = 6.0 EXACT rounds at 2 blk/CU; XCD = rt-band.
__global__ __launch_bounds__(512, 4) void qkv_gemm(
    const u16* __restrict__ xb,
    const u16* __restrict__ wq, const u16* __restrict__ wk, const u16* __restrict__ wv,
    const float* __restrict__ bq, const float* __restrict__ bk, const float* __restrict__ bv,
    u16* __restrict__ Qs, u16* __restrict__ Kb, u16* __restrict__ Vb) {
  const int lin = blockIdx.x;
  const int xcd = lin & 7, inner = lin >> 3;          // inner: 0..191
  const int rt = xcd * 16 + (inner & 15);
  const int ct = inner >> 4;                          // 0..11 over 3 mats
  const int mat = ct >> 2;
  const u16* W = mat == 0 ? wq : (mat == 1 ? wk : wv);
  const float* bias = mat == 0 ? bq : (mat == 1 ? bk : bv);
  u16* out = mat == 0 ? Qs : (mat == 1 ? Kb : Vb);
  const float scl = mat == 0 ? INV_SCALE : 1.0f;
  const int rbase = rt * 128, cbase = (ct & 3) * 192;

  f32x4 acc[4][3] = {};
  gemm128<D_ / 64>(xb + (long)rbase * D_, D_, W + (long)cbase * D_, D_, acc);

  const int l = threadIdx.x & 63, w = threadIdx.x >> 6;
  const int lr = l & 15, orow = (l >> 4) * 4;
  const int wm = w >> 2, wn = w & 3;
  #pragma unroll
  for (int mf = 0; mf < 4; ++mf)
    #pragma unroll
    for (int nf = 0; nf < 3; ++nf) {
      int col = cbase + wn * 48 + nf * 16 + lr;
      float bc = bias[col];
      #pragma unroll
      for (int r = 0; r < 4; ++r) {
        int row = rbase + wm * 64 + mf * 16 + orow + r;
        out[(long)row * D_ + col] = f2bf((acc[mf][nf][r] + bc) * scl);
      }
    }
}

// ---------------- K2: P = exp(Q.K^T) bf16, den partials ----------------
// grid 512 = 2.0 exact rounds; XCD = one b.
__global__ __launch_bounds__(512, 1) void qk_exp(
    const u16* __restrict__ Qs, const u16* __restrict__ Kb,
    u16* __restrict__ P, float* __restrict__ denpart) {
  const int lin = blockIdx.x;
  const int b = lin & 7, inner = lin >> 3;
  const int kblk = inner & 7, qblk = inner >> 3;

  f32x4 acc[8][4] = {};
  gemm256<D_ / 64, 4>(Qs + ((long)b * N_ + qblk * 256) * D_, D_,
                      Kb + ((long)b * N_ + kblk * 256) * D_, D_, acc);

  const int tt = threadIdx.x, l = tt & 63, w = tt >> 6;
  const int lr = l & 15, orow = (l >> 4) * 4;
  const int wm = w >> 2, wn = w & 3;
  float csum[4] = {0.f, 0.f, 0.f, 0.f};
  #pragma unroll
  for (int mf = 0; mf < 8; ++mf)
    #pragma unroll
    for (int nf = 0; nf < 4; ++nf) {
      long kk = kblk * 256 + wn * 64 + nf * 16 + lr;
      #pragma unroll
      for (int r = 0; r < 4; ++r) {
        long q = qblk * 256 + wm * 128 + mf * 16 + orow + r;
        float e = __expf(acc[mf][nf][r]);
        u16 pe = f2bf(e);
        P[((long)b * N_ + q) * N_ + kk] = pe;
        csum[nf] += bf2f(pe);
      }
    }
  #pragma unroll
  for (int nf = 0; nf < 4; ++nf) {
    csum[nf] += __shfl_xor(csum[nf], 16);
    csum[nf] += __shfl_xor(csum[nf], 32);
  }
  if (l < 16) {
    #pragma unroll
    for (int nf = 0; nf < 4; ++nf)
      denpart[((long)(qblk * 2 + wm) * B_ + b) * N_ +
              kblk * 256 + wn * 64 + nf * 16 + l] = csum[nf];
  }
}

// ---------------- K3: VsT[b][d][k] = V[b][k][d] / den[b][k] ----------------
__global__ __launch_bounds__(256) void scale_transpose(
    const u16* __restrict__ Vb, const float* __restrict__ denpart,
    u16* __restrict__ VsT) {
  const int b = blockIdx.z, k0 = blockIdx.y * 64, d0 = blockIdx.x * 64;
  __shared__ float tile[64][65];
  __shared__ float invden[64];
  const int t = threadIdx.x;
  if (t < 64) {
    float s = 0.f;
    for (int qs = 0; qs < 16; ++qs)
      s += denpart[((long)qs * B_ + b) * N_ + k0 + t];
    invden[t] = 1.0f / s;
  }
  __syncthreads();
  #pragma unroll
  for (int h = 0; h < 2; ++h) {
    const int kl = (t >> 3) + h * 32;
    const int d8 = (t & 7) * 8;
    bf16x8 v = *(const bf16x8*)(Vb + ((long)b * N_ + k0 + kl) * D_ + d0 + d8);
    const float s = invden[kl];
    #pragma unroll
    for (int j = 0; j < 8; ++j)
      tile[d8 + j][kl] = bf2f((u16)v[j]) * s;
  }
  __syncthreads();
  #pragma unroll
  for (int h = 0; h < 2; ++h) {
    const int dl = (t >> 3) + h * 32;
    const int k8 = (t & 7) * 8;
    u16x8 o;
    #pragma unroll
    for (int j = 0; j < 8; ++j)
      o[j] = f2bf(tile[dl][k8 + j]);
    *(u16x8*)(VsT + ((long)b * D_ + d0 + dl) * N_ + k0 + k8) = o;
  }
}

// ---------------- K4: out = P @ Vs + xb (bf16 residual) ----------------
// tile 128x192 -> grid 512 = 2.0 EXACT rounds, 2 blk/CU; XCD = one b.
__global__ __launch_bounds__(512, 4) void pv_gemm(
    const u16* __restrict__ P, const u16* __restrict__ VsT,
    const u16* __restrict__ xb, float* __restrict__ out) {
  const int lin = blockIdx.x;
  const int b = lin & 7, inner = lin >> 3;            // inner: 0..63
  const int qt = inner & 15, dt = inner >> 4;         // 16 qt x 4 dt
  const int q0 = qt * 128, d0 = dt * 192;

  f32x4 acc[4][3] = {};
  gemm128<N_ / 64>(P + ((long)b * N_ + q0) * N_, N_,
                   VsT + ((long)b * D_ + d0) * N_, N_, acc);

  const int l = threadIdx.x & 63, w = threadIdx.x >> 6;
  const int lr = l & 15, orow = (l >> 4) * 4;
  const int wm = w >> 2, wn = w & 3;
  #pragma unroll
  for (int mf = 0; mf < 4; ++mf)
    #pragma unroll
    for (int nf = 0; nf < 3; ++nf) {
      int dd = d0 + wn * 48 + nf * 16 + lr;
      #pragma unroll
      for (int r = 0; r < 4; ++r) {
        int q = q0 + wm * 64 + mf * 16 + orow + r;
        long idx = ((long)b * N_ + q) * D_ + dd;
        out[idx] = acc[mf][nf][r] + bf2f(xb[idx]);
      }
    }
}

extern "C" void kernel_launch(void* const* d_in, const int* in_sizes, int n_in,
                              void* d_out, int out_size, void* d_ws, size_t ws_size,
                              hipStream_t stream) {
  const float* x  = (const float*)d_in[0];
  const float* Wq = (const float*)d_in[1];
  const float* bq = (const float*)d_in[2];
  const float* Wk = (const float*)d_in[3];
  const float* bk = (const float*)d_in[4];
  const float* Wv = (const float*)d_in[5];
  const float* bv = (const float*)d_in[6];

  char* ws = (char*)d_ws;
  u16* xb  = (u16*)(ws + 0);                          // 25165824 B (live to pv)
  u16* wqb = (u16*)(ws + 25165824);
  u16* wkb = (u16*)(ws + 26345472);
  u16* wvb = (u16*)(ws + 27525120);
  u16* Qs  = (u16*)(ws + 28704768);
  u16* Kb  = (u16*)(ws + 53870592);
  u16* Vb  = (u16*)(ws + 79036416);
  u16* VsT = (u16*)(ws + 104202240);                  // 25165824 B
  u16* P   = (u16*)(ws + 129368064);                  // 67108864 B
  float* denpart = (float*)(ws + 196476928);          // 1048576 B
  (void)in_sizes; (void)n_in; (void)out_size; (void)ws_size;

  cast_kernel<<<7008, 256, 0, stream>>>(x, Wq, Wk, Wv, xb, wqb, wkb, wvb);
  qkv_gemm<<<1536, 512, 0, stream>>>(xb, wqb, wkb, wvb, bq, bk, bv, Qs, Kb, Vb);
  qk_exp<<<512, 512, 0, stream>>>(Qs, Kb, P, denpart);
  scale_transpose<<<dim3(12, 32, 8), 256, 0, stream>>>(Vb, denpart, VsT);
  pv_gemm<<<512, 512, 0, stream>>>(P, VsT, xb, (float*)d_out);
}